// Round 6
// baseline (1829.253 us; speedup 1.0000x reference)
//
#include <hip/hip_runtime.h>

// HeteroSAGE on MI355X — round 9: scatter-fused aggregation.
// R8 post-mortem: fusion works (700us; FUSED-A at 1.3 TB/s). Remaining cost
// is spread over gather_means (~118us re-reading h_tx0 randomly), CSR build,
// and small GEMMs. Structure: e_tx_c = e_tx_m = arange(E), so aggregation is
// a pure scatter-add of h_tx0 rows keyed by e_card/e_merch — indices FUSED-A
// already holds. This round: FUSED-A scatters f32 atomicAdds into agg_card/
// agg_merch in its epilogue; h_tx0 never hits HBM; gather_mean + scan2 +
// place + eidx all deleted; mean = agg * (1/cnt) folded into the card/merch
// update GEMM A-load (a_f32==2 mode, cnt = degree histogram).

#define N_TX    200000
#define N_CARD  50000
#define N_MERCH 10000
#define NE      200000

typedef __attribute__((ext_vector_type(8))) short short8;
typedef __attribute__((ext_vector_type(4))) float f32x4;

__device__ inline unsigned short f2b(float f) {
    unsigned u = __builtin_bit_cast(unsigned, f);
    unsigned r = (u + 0x7fffu + ((u >> 16) & 1u)) >> 16;   // RNE
    return (unsigned short)r;
}
__device__ inline float b2f(unsigned short s) {
    return __builtin_bit_cast(float, (unsigned)s << 16);
}

// ---------------------------------------------------------------------------
// Fused two-GEMM kernel. 64-row tiles, 4 waves, one 16-row m-tile per wave.
// mode A (h2w == null):  h0 = relu(A@W1 + b1)  (LDS only; atomic-scattered
//                         into AGG1[I1[r]] / AGG2[I2[r]] as f32)
//                         out = relu(h0@W2 + b2 + P1[I1]+P2[I2]) -> OUT1 bf16
// mode B (h2w != null):  h  = relu(A@W1 + b1 + P1[I1]+P2[I2])   (LDS only)
//                         out[r] = relu(h@W2 + b2) . h2w + h2b   -> OUT1 f32
// A: f32 (a_f32=1) or bf16, [M][128]. W1T/W2T bf16 [128][128] pre-transposed.
__global__ __launch_bounds__(256, 3) void fused2(
    const void* __restrict__ A, int a_f32,
    const unsigned short* __restrict__ W1T, const float* __restrict__ b1,
    const unsigned short* __restrict__ W2T, const float* __restrict__ b2,
    const unsigned short* __restrict__ P1, const int* __restrict__ I1,
    const unsigned short* __restrict__ P2, const int* __restrict__ I2,
    float* __restrict__ AGG1, float* __restrict__ AGG2,
    const float* __restrict__ h2w, const float* __restrict__ h2b,
    void* __restrict__ OUT1, int M)
{
    __shared__ float Tf[64 * 132];            // fp32 transpose tile
    __shared__ unsigned short Tb[64 * 136];   // bf16 stage-2 A tile
    const int tid  = threadIdx.x;
    const int wave = tid >> 6;
    const int lane = tid & 63;
    const int quad = lane >> 4;
    const int l15  = lane & 15;
    const int base = blockIdx.x * 64;
    const int rgrp = tid >> 4;                // 0..15: row-pass row group
    const int c0   = l15 * 8;                 // row-pass column block
    const bool modeA = (h2w == nullptr);

    // prologue: row-pass gather/scatter indices (latency hidden by stage 1)
    int idx1[4], idx2[4];
#pragma unroll
    for (int p = 0; p < 4; ++p) {
        int r = base + p * 16 + rgrp;
        int rc = (r < M) ? r : 0;
        idx1[p] = I1 ? I1[rc] : 0;
        idx2[p] = I2 ? I2[rc] : 0;
    }

    // ---- stage 1: A-frags from global
    short8 af[4];
    {
        int r = base + wave * 16 + l15;
        int rc = (r < M) ? r : 0;
        if (a_f32) {
            const float* ap = (const float*)A + (size_t)rc * 128 + quad * 8;
#pragma unroll
            for (int kk = 0; kk < 4; ++kk) {
                float4 u = *reinterpret_cast<const float4*>(ap + kk * 32);
                float4 v = *reinterpret_cast<const float4*>(ap + kk * 32 + 4);
                short8 t;
                t[0] = (short)f2b(u.x); t[1] = (short)f2b(u.y);
                t[2] = (short)f2b(u.z); t[3] = (short)f2b(u.w);
                t[4] = (short)f2b(v.x); t[5] = (short)f2b(v.y);
                t[6] = (short)f2b(v.z); t[7] = (short)f2b(v.w);
                af[kk] = t;
            }
        } else {
            const unsigned short* ap =
                (const unsigned short*)A + (size_t)rc * 128 + quad * 8;
#pragma unroll
            for (int kk = 0; kk < 4; ++kk)
                af[kk] = *reinterpret_cast<const short8*>(ap + kk * 32);
        }
    }

    f32x4 acc[8];
#pragma unroll
    for (int nt = 0; nt < 8; ++nt) acc[nt] = (f32x4){0.f, 0.f, 0.f, 0.f};
#pragma unroll
    for (int nt = 0; nt < 8; ++nt) {
        const unsigned short* bp = W1T + (nt * 16 + l15) * 128 + quad * 8;
#pragma unroll
        for (int kk = 0; kk < 4; ++kk) {
            short8 bf = *reinterpret_cast<const short8*>(bp + kk * 32);
            acc[nt] = __builtin_amdgcn_mfma_f32_16x16x32_bf16(
                af[kk], bf, acc[nt], 0, 0, 0);
        }
    }

    // P-row gathers (only depend on idx; hide under transpose + barrier)
    short8 p1v[4], p2v[4];
    if (P1) {
#pragma unroll
        for (int p = 0; p < 4; ++p)
            p1v[p] = *reinterpret_cast<const short8*>(
                P1 + (size_t)idx1[p] * 128 + c0);
    }
    if (P2) {
#pragma unroll
        for (int p = 0; p < 4; ++p)
            p2v[p] = *reinterpret_cast<const short8*>(
                P2 + (size_t)idx2[p] * 128 + c0);
    }

    // ---- transpose stage-1 result
    const int lrow0 = wave * 16 + quad * 4;
    if (modeA) {
        // h0 = relu(acc + b1) -> bf16 tile (this IS h_tx0, LDS-resident only)
#pragma unroll
        for (int nt = 0; nt < 8; ++nt) {
            float bb = b1 ? b1[nt * 16 + l15] : 0.f;
#pragma unroll
            for (int reg = 0; reg < 4; ++reg)
                Tb[(lrow0 + reg) * 136 + nt * 16 + l15] =
                    f2b(fmaxf(acc[nt][reg] + bb, 0.f));
        }
    } else {
        // raw fp32 z -> Tf (bias/P/relu applied in row-pass)
#pragma unroll
        for (int nt = 0; nt < 8; ++nt)
#pragma unroll
            for (int reg = 0; reg < 4; ++reg)
                Tf[(lrow0 + reg) * 132 + nt * 16 + l15] = acc[nt][reg];
    }
    __syncthreads();

    if (modeA) {
        // scatter-add h0 rows into agg buffers (aggregation fused here;
        // e_tx is arange so each tx row contributes exactly once)
#pragma unroll
        for (int p = 0; p < 4; ++p) {
            const int rloc = p * 16 + rgrp;
            const int r = base + rloc;
            if (r < M) {
                short8 hv = *reinterpret_cast<const short8*>(&Tb[rloc * 136 + c0]);
                float* a1 = AGG1 + (size_t)idx1[p] * 128 + c0;
                float* a2 = AGG2 + (size_t)idx2[p] * 128 + c0;
#pragma unroll
                for (int j = 0; j < 8; ++j) {
                    float v = b2f((unsigned short)hv[j]);
                    atomicAdd(a1 + j, v);
                    atomicAdd(a2 + j, v);
                }
            }
        }
    } else {
        // row-pass 1: h = relu(z + b1 + P1 + P2) -> bf16 tile
        float b1r[8];
#pragma unroll
        for (int j = 0; j < 8; ++j) b1r[j] = b1 ? b1[c0 + j] : 0.f;
#pragma unroll
        for (int p = 0; p < 4; ++p) {
            const int rloc = p * 16 + rgrp;
            float4 u = *reinterpret_cast<const float4*>(&Tf[rloc * 132 + c0]);
            float4 v = *reinterpret_cast<const float4*>(&Tf[rloc * 132 + c0 + 4]);
            float o[8] = {u.x, u.y, u.z, u.w, v.x, v.y, v.z, v.w};
            short8 ov;
#pragma unroll
            for (int j = 0; j < 8; ++j) {
                float t = o[j] + b1r[j];
                if (P1) t += b2f((unsigned short)p1v[p][j]);
                if (P2) t += b2f((unsigned short)p2v[p][j]);
                ov[j] = (short)f2b(fmaxf(t, 0.f));
            }
            *reinterpret_cast<short8*>(&Tb[rloc * 136 + c0]) = ov;
        }
        __syncthreads();
    }

    // ---- stage 2: A-frags from the bf16 tile
    short8 af2[4];
#pragma unroll
    for (int kk = 0; kk < 4; ++kk)
        af2[kk] = *reinterpret_cast<const short8*>(
            &Tb[(wave * 16 + l15) * 136 + quad * 8 + kk * 32]);

    f32x4 acc2[8];
#pragma unroll
    for (int nt = 0; nt < 8; ++nt) acc2[nt] = (f32x4){0.f, 0.f, 0.f, 0.f};
#pragma unroll
    for (int nt = 0; nt < 8; ++nt) {
        const unsigned short* bp = W2T + (nt * 16 + l15) * 128 + quad * 8;
#pragma unroll
        for (int kk = 0; kk < 4; ++kk) {
            short8 bf = *reinterpret_cast<const short8*>(bp + kk * 32);
            acc2[nt] = __builtin_amdgcn_mfma_f32_16x16x32_bf16(
                af2[kk], bf, acc2[nt], 0, 0, 0);
        }
    }

    if (!modeA) {
        // head in C-layout: o = relu(acc2 + b2); logit = o . h2w + h2b
        float hsum[4] = {0.f, 0.f, 0.f, 0.f};
#pragma unroll
        for (int nt = 0; nt < 8; ++nt) {
            float bb = b2 ? b2[nt * 16 + l15] : 0.f;
            float w = h2w[nt * 16 + l15];
#pragma unroll
            for (int reg = 0; reg < 4; ++reg) {
                float o = fmaxf(acc2[nt][reg] + bb, 0.f);
                hsum[reg] += o * w;
            }
        }
        float* OUTf = (float*)OUT1;
#pragma unroll
        for (int reg = 0; reg < 4; ++reg) {
            float h = hsum[reg];
            h += __shfl_xor(h, 1);
            h += __shfl_xor(h, 2);
            h += __shfl_xor(h, 4);
            h += __shfl_xor(h, 8);
            int r = base + wave * 16 + quad * 4 + reg;
            if (l15 == 0 && r < M) OUTf[r] = h + h2b[0];
        }
    } else {
        // transpose stage-2, then row-pass 2: +b2+P, relu -> OUT1 bf16
#pragma unroll
        for (int nt = 0; nt < 8; ++nt)
#pragma unroll
            for (int reg = 0; reg < 4; ++reg)
                Tf[(lrow0 + reg) * 132 + nt * 16 + l15] = acc2[nt][reg];
        __syncthreads();
        float b2r[8];
#pragma unroll
        for (int j = 0; j < 8; ++j) b2r[j] = b2 ? b2[c0 + j] : 0.f;
        unsigned short* OB = (unsigned short*)OUT1;
#pragma unroll
        for (int p = 0; p < 4; ++p) {
            const int rloc = p * 16 + rgrp;
            const int r = base + rloc;
            float4 u = *reinterpret_cast<const float4*>(&Tf[rloc * 132 + c0]);
            float4 v = *reinterpret_cast<const float4*>(&Tf[rloc * 132 + c0 + 4]);
            float o[8] = {u.x, u.y, u.z, u.w, v.x, v.y, v.z, v.w};
            short8 ov;
#pragma unroll
            for (int j = 0; j < 8; ++j) {
                float t = o[j] + b2r[j];
                if (P1) t += b2f((unsigned short)p1v[p][j]);
                if (P2) t += b2f((unsigned short)p2v[p][j]);
                ov[j] = (short)f2b(fmaxf(t, 0.f));
            }
            if (r < M)
                *reinterpret_cast<short8*>(OB + (size_t)r * 128 + c0) = ov;
        }
    }
}

// ---------------------------------------------------------------------------
// Basic GEMM: encoders (f32 A, optional rowIdx), p-GEMMs, card/merch updates.
// a1_f32: 0=bf16, 1=f32, 2=f32 scaled by 1/max(cnt1[row],1) (mean-from-agg).
// Block: 64 rows x 128 cols; 4 waves.
__global__ __launch_bounds__(256, 4) void mfma_gemm(
    const void* __restrict__ A1, int a1_f32, const int* __restrict__ rowIdx1,
    const int* __restrict__ cnt1,
    int K1, const unsigned short* __restrict__ WT1,
    const void* __restrict__ A2, int K2, const unsigned short* __restrict__ WT2,
    const float* __restrict__ bias,
    int do_relu, void* __restrict__ OUT, int M)
{
    __shared__ unsigned short Ts[64 * 136];
    const int tid  = threadIdx.x;
    const int wave = tid >> 6;
    const int lane = tid & 63;
    const int quad = lane >> 4;
    const int l15  = lane & 15;
    const int base = blockIdx.x * 64;
    const int rgrp = tid >> 4;
    const int c0   = l15 * 8;

    f32x4 acc[8];
#pragma unroll
    for (int nt = 0; nt < 8; ++nt)
        acc[nt] = (f32x4){0.f, 0.f, 0.f, 0.f};

    for (int pass = 0; pass < 2; ++pass) {
        const void* A = (pass == 0) ? A1 : A2;
        if (!A) break;
        const int K = (pass == 0) ? K1 : K2;
        const unsigned short* WTg = (pass == 0) ? WT1 : WT2;
        const int* rIdx = (pass == 0) ? rowIdx1 : nullptr;
        const int a_f32 = (pass == 0) ? a1_f32 : 0;
        const int nkk = K >> 5;

        short8 af[4];
        {
            int r = base + wave * 16 + l15;
            int rc = (r < M) ? r : 0;
            int ar = rIdx ? rIdx[rc] : rc;
            if (a_f32) {
                float inv = 1.0f;
                if (a_f32 == 2) {
                    int c = cnt1[ar];
                    inv = 1.0f / (float)(c > 0 ? c : 1);
                }
                const float* ap = (const float*)A + (size_t)ar * K + quad * 8;
#pragma unroll
                for (int kk = 0; kk < 4; ++kk) if (kk < nkk) {
                    float4 u = *reinterpret_cast<const float4*>(ap + kk * 32);
                    float4 v = *reinterpret_cast<const float4*>(ap + kk * 32 + 4);
                    short8 t;
                    t[0] = (short)f2b(u.x * inv); t[1] = (short)f2b(u.y * inv);
                    t[2] = (short)f2b(u.z * inv); t[3] = (short)f2b(u.w * inv);
                    t[4] = (short)f2b(v.x * inv); t[5] = (short)f2b(v.y * inv);
                    t[6] = (short)f2b(v.z * inv); t[7] = (short)f2b(v.w * inv);
                    af[kk] = t;
                }
            } else {
                const unsigned short* ap =
                    (const unsigned short*)A + (size_t)ar * K + quad * 8;
#pragma unroll
                for (int kk = 0; kk < 4; ++kk) if (kk < nkk)
                    af[kk] = *reinterpret_cast<const short8*>(ap + kk * 32);
            }
        }

#pragma unroll
        for (int nt = 0; nt < 8; ++nt) {
            short8 bf[4];
            const unsigned short* bp = WTg + (nt * 16 + l15) * K + quad * 8;
#pragma unroll
            for (int kk = 0; kk < 4; ++kk) if (kk < nkk)
                bf[kk] = *reinterpret_cast<const short8*>(bp + kk * 32);
#pragma unroll
            for (int kk = 0; kk < 4; ++kk) if (kk < nkk)
                acc[nt] = __builtin_amdgcn_mfma_f32_16x16x32_bf16(
                    af[kk], bf[kk], acc[nt], 0, 0, 0);
        }
    }

#pragma unroll
    for (int nt = 0; nt < 8; ++nt) {
        int col = nt * 16 + l15;
        int lrow0 = wave * 16 + quad * 4;
#pragma unroll
        for (int reg = 0; reg < 4; ++reg)
            Ts[(lrow0 + reg) * 136 + col] = f2b(acc[nt][reg]);
    }

    float bias8[8];
#pragma unroll
    for (int j = 0; j < 8; ++j)
        bias8[j] = bias ? bias[c0 + j] : 0.f;

    __syncthreads();

    unsigned short* OUTb = (unsigned short*)OUT;
#pragma unroll
    for (int p = 0; p < 4; ++p) {
        const int rloc = p * 16 + rgrp;
        const int r = base + rloc;
        if (r >= M) continue;
        short8 av = *reinterpret_cast<const short8*>(&Ts[rloc * 136 + c0]);
        short8 ov;
#pragma unroll
        for (int j = 0; j < 8; ++j) {
            float o = b2f((unsigned short)av[j]) + bias8[j];
            if (do_relu) o = fmaxf(o, 0.f);
            ov[j] = (short)f2b(o);
        }
        *reinterpret_cast<short8*>(OUTb + (size_t)r * 128 + c0) = ov;
    }
}

// ---------------------------------------------------------------------------
// Weight prep: fp32 [K][128] -> bf16 transposed [128][K]; job 6/13 also does
// Wsum=Wr0+Wr2 and bsum=bl0+bl2. 18 jobs x 16384-short slots.
__global__ __launch_bounds__(256) void convert_weights(
    const float* __restrict__ tx_W, const float* __restrict__ card_proj_W,
    const float* __restrict__ merch_proj_W, const float* __restrict__ h1_W,
    const float* __restrict__ conv_Wl, const float* __restrict__ conv_Wr,
    const float* __restrict__ conv_bl,
    unsigned short* __restrict__ WT, float* __restrict__ bsum)
{
    int job = blockIdx.y;
    int K = 128;
    const float* src = nullptr;
    const float* src2 = nullptr;
    if (job == 0) src = tx_W;
    else if (job == 1) { src = card_proj_W; K = 64; }
    else if (job == 2) { src = merch_proj_W; K = 64; }
    else if (job == 3) src = h1_W;
    else {
        int l = (job - 4) / 7, e = (job - 4) % 7;
        const float* Wl = conv_Wl + (size_t)l * 4 * 16384;
        const float* Wr = conv_Wr + (size_t)l * 4 * 16384;
        switch (e) {
            case 0: src = Wl; break;
            case 1: src = Wl + 16384; break;
            case 2: src = Wl + 2 * 16384; break;
            case 3: src = Wl + 3 * 16384; break;
            case 4: src = Wr + 16384; break;
            case 5: src = Wr + 3 * 16384; break;
            default:
                src = Wr; src2 = Wr + 2 * 16384;
                if (blockIdx.x == 0 && threadIdx.x < 128) {
                    const float* bl = conv_bl + (size_t)l * 4 * 128;
                    bsum[l * 128 + threadIdx.x] =
                        bl[threadIdx.x] + bl[2 * 128 + threadIdx.x];
                }
                break;
        }
    }
    int e = blockIdx.x * 256 + threadIdx.x;
    if (e < (K << 7)) {
        int n = (K == 128) ? (e >> 7) : (e >> 6);
        int k = e & (K - 1);
        float v = src[(size_t)k * 128 + n];
        if (src2) v += src2[(size_t)k * 128 + n];
        WT[(size_t)job * 16384 + n * K + k] = f2b(v);
    }
}

// ---------------------------------------------------------------------------
// degree histogram (cnt for mean); edges fixed within call
__global__ __launch_bounds__(256) void hist_kernel(
    const int* __restrict__ e_card, const int* __restrict__ e_merch,
    int* __restrict__ hist_c, int* __restrict__ hist_m, int E)
{
    int i = blockIdx.x * 256 + threadIdx.x;
    if (i < E) {
        atomicAdd(&hist_c[e_card[i]], 1);
        atomicAdd(&hist_m[e_merch[i]], 1);
    }
}

// ---------------------------------------------------------------------------
extern "C" void kernel_launch(void* const* d_in, const int* in_sizes, int n_in,
                              void* d_out, int out_size, void* d_ws, size_t ws_size,
                              hipStream_t stream)
{
    const float* tx_x        = (const float*)d_in[0];
    const int*   card_ids    = (const int*)d_in[1];
    const int*   merch_ids   = (const int*)d_in[2];
    const int*   e_card      = (const int*)d_in[3];
    const int*   e_tx_c      = (const int*)d_in[4];
    const int*   e_merch     = (const int*)d_in[5];
    const int*   e_tx_m      = (const int*)d_in[6];
    const float* card_emb    = (const float*)d_in[7];
    const float* merch_emb   = (const float*)d_in[8];
    const float* card_proj_W = (const float*)d_in[9];
    const float* card_proj_b = (const float*)d_in[10];
    const float* merch_proj_W= (const float*)d_in[11];
    const float* merch_proj_b= (const float*)d_in[12];
    const float* tx_W        = (const float*)d_in[13];
    const float* tx_b        = (const float*)d_in[14];
    const float* conv_Wl     = (const float*)d_in[15];
    const float* conv_bl     = (const float*)d_in[16];
    const float* conv_Wr     = (const float*)d_in[17];
    const float* h1_W        = (const float*)d_in[18];
    const float* h1_b        = (const float*)d_in[19];
    const float* h2_W        = (const float*)d_in[20];
    const float* h2_b        = (const float*)d_in[21];

    char* wsb = (char*)d_ws;
    auto alloc = [&](size_t bytes) {
        char* p = wsb; wsb += (bytes + 255) & ~(size_t)255; return p;
    };
    unsigned short* h_tx1   = (unsigned short*)alloc((size_t)N_TX * 128 * 2);
    unsigned short* h_card  = (unsigned short*)alloc((size_t)N_CARD * 128 * 2);
    unsigned short* h_merch = (unsigned short*)alloc((size_t)N_MERCH * 128 * 2);
    unsigned short* p_card  = (unsigned short*)alloc((size_t)N_CARD * 128 * 2);
    unsigned short* p_merch = (unsigned short*)alloc((size_t)N_MERCH * 128 * 2);
    unsigned short* WT      = (unsigned short*)alloc((size_t)18 * 16384 * 2);
    float* bsum = (float*)alloc(2 * 128 * 4);
    // zero-region: agg_card | agg_merch | hist_c | hist_m (single memset)
    size_t zbytes = ((size_t)N_CARD * 128 + (size_t)N_MERCH * 128) * 4
                  + (size_t)(N_CARD + N_MERCH) * 4;
    float* agg_card  = (float*)alloc(zbytes);
    float* agg_merch = agg_card + (size_t)N_CARD * 128;
    int*   hist_c    = (int*)(agg_merch + (size_t)N_MERCH * 128);
    int*   hist_m    = hist_c + N_CARD;

    auto WTj = [&](int job) { return WT + (size_t)job * 16384; };

    auto gemm_basic = [&](const void* A1, int a1f32, const int* ri,
                          const int* cnt, int K1,
                          const unsigned short* W1, const void* A2, int K2,
                          const unsigned short* W2, const float* bias,
                          int relu, void* out, int M) {
        mfma_gemm<<<dim3((M + 63) / 64), dim3(256), 0, stream>>>(
            A1, a1f32, ri, cnt, K1, W1, A2, K2, W2, bias, relu, out, M);
    };

    // weight prep + zero agg/hist + degree histogram
    convert_weights<<<dim3(64, 18), dim3(256), 0, stream>>>(
        tx_W, card_proj_W, merch_proj_W, h1_W, conv_Wl, conv_Wr, conv_bl,
        WT, bsum);
    hipMemsetAsync(agg_card, 0, zbytes, stream);
    hist_kernel<<<dim3((NE + 255) / 256), dim3(256), 0, stream>>>(
        e_card, e_merch, hist_c, hist_m, NE);

    // card/merch encoders (fp32 A, gathered by ids)
    gemm_basic(card_emb, 1, card_ids, nullptr, 64, WTj(1), nullptr, 0, nullptr,
               card_proj_b, 0, h_card, N_CARD);
    gemm_basic(merch_emb, 1, merch_ids, nullptr, 64, WTj(2), nullptr, 0, nullptr,
               merch_proj_b, 0, h_merch, N_MERCH);

    // layer-1 p projections (h_card0/h_merch0 @ Wl0/Wl2)
    gemm_basic(h_card, 0, nullptr, nullptr, 128, WTj(4), nullptr, 0, nullptr,
               nullptr, 0, p_card, N_CARD);
    gemm_basic(h_merch, 0, nullptr, nullptr, 128, WTj(6), nullptr, 0, nullptr,
               nullptr, 0, p_merch, N_MERCH);

    // FUSED-A: tx encoder + layer-1 tx update + aggregation scatter.
    // h_tx0 = relu(tx_x@txW + txb) stays in LDS; scattered into agg_card/
    // agg_merch; h_tx1 = relu(h_tx0@Wsum1 + bsum1 + p_c[e_c] + p_m[e_m]).
    fused2<<<dim3((N_TX + 63) / 64), dim3(256), 0, stream>>>(
        tx_x, 1, WTj(0), tx_b, WTj(10), bsum,
        p_card, e_card, p_merch, e_merch,
        agg_card, agg_merch, nullptr, nullptr, h_tx1, N_TX);

    // layer-1 card/merch updates: relu((agg/cnt)@Wl + h@Wr + bl)
    gemm_basic(agg_card, 2, nullptr, hist_c, 128, WTj(5), h_card, 128, WTj(8),
               conv_bl + 128, 1, h_card, N_CARD);
    gemm_basic(agg_merch, 2, nullptr, hist_m, 128, WTj(7), h_merch, 128, WTj(9),
               conv_bl + 3 * 128, 1, h_merch, N_MERCH);

    // layer-2 p projections (h_card1/h_merch1 @ Wl0/Wl2 of layer 2)
    gemm_basic(h_card, 0, nullptr, nullptr, 128, WTj(11), nullptr, 0, nullptr,
               nullptr, 0, p_card, N_CARD);
    gemm_basic(h_merch, 0, nullptr, nullptr, 128, WTj(13), nullptr, 0, nullptr,
               nullptr, 0, p_merch, N_MERCH);

    // (layer-2 card/merch updates are dead code — h_card2/h_merch2 never
    //  consumed — skipped, as is their aggregation.)

    // FUSED-B: layer-2 tx update + head. h_tx2 never hits HBM.
    fused2<<<dim3((N_TX + 63) / 64), dim3(256), 0, stream>>>(
        h_tx1, 0, WTj(17), bsum + 128, WTj(3), h1_b,
        p_card, e_card, p_merch, e_merch,
        nullptr, nullptr, h2_W, h2_b, d_out, N_TX);
}

// Round 7
// 675.591 us; speedup vs baseline: 2.7076x; 2.7076x over previous
//
#include <hip/hip_runtime.h>

// HeteroSAGE on MI355X — round 10: revert scatter-atomics; fuse card/merch
// chains. R9 post-mortem: 51M scalar atomics into a 30MB region thrashed
// per-XCD L2 -> WRITE 1.65GB, 1394us. Reverted to R8's gather/CSR (700us).
// New: F1 = encoder + layer1-p-projection (h0 stays in LDS for stage 2);
// F2 = layer1 update + layer2-p-projection (h1 NEVER hits HBM — dual-input
// stage 1, consumed only by stage 2 since layer2 card/merch updates are
// dead). 8 small GEMMs -> 4 fused kernels, ~46MB + 4 launches saved.

#define N_TX    200000
#define N_CARD  50000
#define N_MERCH 10000
#define NE      200000

typedef __attribute__((ext_vector_type(8))) short short8;
typedef __attribute__((ext_vector_type(4))) float f32x4;

__device__ inline unsigned short f2b(float f) {
    unsigned u = __builtin_bit_cast(unsigned, f);
    unsigned r = (u + 0x7fffu + ((u >> 16) & 1u)) >> 16;   // RNE
    return (unsigned short)r;
}
__device__ inline float b2f(unsigned short s) {
    return __builtin_bit_cast(float, (unsigned)s << 16);
}

// ---------------------------------------------------------------------------
// Fused two-GEMM kernel (R8-proven). 64-row tiles, 4 waves, 16-row m-tile/wave.
// mode A (OUT0 != null):  h0 = relu(A@W1 + b1)        -> store OUT0 (bf16)
//                         out = relu(h0@W2 + b2 + P1[I1]+P2[I2]) -> OUT1 bf16
// mode B (OUT0 == null):  h  = relu(A@W1 + b1 + P1[I1]+P2[I2])   (LDS only)
//                         out[r] = relu(h@W2 + b2) . h2w + h2b   -> OUT1 f32
__global__ __launch_bounds__(256, 3) void fused2(
    const void* __restrict__ A, int a_f32,
    const unsigned short* __restrict__ W1T, const float* __restrict__ b1,
    const unsigned short* __restrict__ W2T, const float* __restrict__ b2,
    const unsigned short* __restrict__ P1, const int* __restrict__ I1,
    const unsigned short* __restrict__ P2, const int* __restrict__ I2,
    unsigned short* __restrict__ OUT0,
    const float* __restrict__ h2w, const float* __restrict__ h2b,
    void* __restrict__ OUT1, int M)
{
    __shared__ float Tf[64 * 132];            // fp32 transpose tile
    __shared__ unsigned short Tb[64 * 136];   // bf16 stage-2 A tile
    const int tid  = threadIdx.x;
    const int wave = tid >> 6;
    const int lane = tid & 63;
    const int quad = lane >> 4;
    const int l15  = lane & 15;
    const int base = blockIdx.x * 64;
    const int rgrp = tid >> 4;                // 0..15: row-pass row group
    const int c0   = l15 * 8;                 // row-pass column block
    const bool modeA = (OUT0 != nullptr);

    int idx1[4], idx2[4];
#pragma unroll
    for (int p = 0; p < 4; ++p) {
        int r = base + p * 16 + rgrp;
        int rc = (r < M) ? r : 0;
        idx1[p] = I1 ? I1[rc] : 0;
        idx2[p] = I2 ? I2[rc] : 0;
    }

    short8 af[4];
    {
        int r = base + wave * 16 + l15;
        int rc = (r < M) ? r : 0;
        if (a_f32) {
            const float* ap = (const float*)A + (size_t)rc * 128 + quad * 8;
#pragma unroll
            for (int kk = 0; kk < 4; ++kk) {
                float4 u = *reinterpret_cast<const float4*>(ap + kk * 32);
                float4 v = *reinterpret_cast<const float4*>(ap + kk * 32 + 4);
                short8 t;
                t[0] = (short)f2b(u.x); t[1] = (short)f2b(u.y);
                t[2] = (short)f2b(u.z); t[3] = (short)f2b(u.w);
                t[4] = (short)f2b(v.x); t[5] = (short)f2b(v.y);
                t[6] = (short)f2b(v.z); t[7] = (short)f2b(v.w);
                af[kk] = t;
            }
        } else {
            const unsigned short* ap =
                (const unsigned short*)A + (size_t)rc * 128 + quad * 8;
#pragma unroll
            for (int kk = 0; kk < 4; ++kk)
                af[kk] = *reinterpret_cast<const short8*>(ap + kk * 32);
        }
    }

    f32x4 acc[8];
#pragma unroll
    for (int nt = 0; nt < 8; ++nt) acc[nt] = (f32x4){0.f, 0.f, 0.f, 0.f};
#pragma unroll
    for (int nt = 0; nt < 8; ++nt) {
        const unsigned short* bp = W1T + (nt * 16 + l15) * 128 + quad * 8;
#pragma unroll
        for (int kk = 0; kk < 4; ++kk) {
            short8 bf = *reinterpret_cast<const short8*>(bp + kk * 32);
            acc[nt] = __builtin_amdgcn_mfma_f32_16x16x32_bf16(
                af[kk], bf, acc[nt], 0, 0, 0);
        }
    }

    // P-row gathers (hide under transpose + barrier)
    short8 p1v[4], p2v[4];
    if (P1) {
#pragma unroll
        for (int p = 0; p < 4; ++p)
            p1v[p] = *reinterpret_cast<const short8*>(
                P1 + (size_t)idx1[p] * 128 + c0);
    }
    if (P2) {
#pragma unroll
        for (int p = 0; p < 4; ++p)
            p2v[p] = *reinterpret_cast<const short8*>(
                P2 + (size_t)idx2[p] * 128 + c0);
    }

    const int lrow0 = wave * 16 + quad * 4;
    if (modeA) {
#pragma unroll
        for (int nt = 0; nt < 8; ++nt) {
            float bb = b1 ? b1[nt * 16 + l15] : 0.f;
#pragma unroll
            for (int reg = 0; reg < 4; ++reg)
                Tb[(lrow0 + reg) * 136 + nt * 16 + l15] =
                    f2b(fmaxf(acc[nt][reg] + bb, 0.f));
        }
    } else {
#pragma unroll
        for (int nt = 0; nt < 8; ++nt)
#pragma unroll
            for (int reg = 0; reg < 4; ++reg)
                Tf[(lrow0 + reg) * 132 + nt * 16 + l15] = acc[nt][reg];
    }
    __syncthreads();

    if (modeA) {
#pragma unroll
        for (int p = 0; p < 4; ++p) {
            const int rloc = p * 16 + rgrp;
            const int r = base + rloc;
            if (r < M) {
                short8 hv = *reinterpret_cast<const short8*>(&Tb[rloc * 136 + c0]);
                *reinterpret_cast<short8*>(OUT0 + (size_t)r * 128 + c0) = hv;
            }
        }
    } else {
        float b1r[8];
#pragma unroll
        for (int j = 0; j < 8; ++j) b1r[j] = b1 ? b1[c0 + j] : 0.f;
#pragma unroll
        for (int p = 0; p < 4; ++p) {
            const int rloc = p * 16 + rgrp;
            float4 u = *reinterpret_cast<const float4*>(&Tf[rloc * 132 + c0]);
            float4 v = *reinterpret_cast<const float4*>(&Tf[rloc * 132 + c0 + 4]);
            float o[8] = {u.x, u.y, u.z, u.w, v.x, v.y, v.z, v.w};
            short8 ov;
#pragma unroll
            for (int j = 0; j < 8; ++j) {
                float t = o[j] + b1r[j];
                if (P1) t += b2f((unsigned short)p1v[p][j]);
                if (P2) t += b2f((unsigned short)p2v[p][j]);
                ov[j] = (short)f2b(fmaxf(t, 0.f));
            }
            *reinterpret_cast<short8*>(&Tb[rloc * 136 + c0]) = ov;
        }
        __syncthreads();
    }

    short8 af2[4];
#pragma unroll
    for (int kk = 0; kk < 4; ++kk)
        af2[kk] = *reinterpret_cast<const short8*>(
            &Tb[(wave * 16 + l15) * 136 + quad * 8 + kk * 32]);

    f32x4 acc2[8];
#pragma unroll
    for (int nt = 0; nt < 8; ++nt) acc2[nt] = (f32x4){0.f, 0.f, 0.f, 0.f};
#pragma unroll
    for (int nt = 0; nt < 8; ++nt) {
        const unsigned short* bp = W2T + (nt * 16 + l15) * 128 + quad * 8;
#pragma unroll
        for (int kk = 0; kk < 4; ++kk) {
            short8 bf = *reinterpret_cast<const short8*>(bp + kk * 32);
            acc2[nt] = __builtin_amdgcn_mfma_f32_16x16x32_bf16(
                af2[kk], bf, acc2[nt], 0, 0, 0);
        }
    }

    if (!modeA) {
        float hsum[4] = {0.f, 0.f, 0.f, 0.f};
#pragma unroll
        for (int nt = 0; nt < 8; ++nt) {
            float bb = b2 ? b2[nt * 16 + l15] : 0.f;
            float w = h2w[nt * 16 + l15];
#pragma unroll
            for (int reg = 0; reg < 4; ++reg) {
                float o = fmaxf(acc2[nt][reg] + bb, 0.f);
                hsum[reg] += o * w;
            }
        }
        float* OUTf = (float*)OUT1;
#pragma unroll
        for (int reg = 0; reg < 4; ++reg) {
            float h = hsum[reg];
            h += __shfl_xor(h, 1);
            h += __shfl_xor(h, 2);
            h += __shfl_xor(h, 4);
            h += __shfl_xor(h, 8);
            int r = base + wave * 16 + quad * 4 + reg;
            if (l15 == 0 && r < M) OUTf[r] = h + h2b[0];
        }
    } else {
#pragma unroll
        for (int nt = 0; nt < 8; ++nt)
#pragma unroll
            for (int reg = 0; reg < 4; ++reg)
                Tf[(lrow0 + reg) * 132 + nt * 16 + l15] = acc2[nt][reg];
        __syncthreads();
        float b2r[8];
#pragma unroll
        for (int j = 0; j < 8; ++j) b2r[j] = b2 ? b2[c0 + j] : 0.f;
        unsigned short* OB = (unsigned short*)OUT1;
#pragma unroll
        for (int p = 0; p < 4; ++p) {
            const int rloc = p * 16 + rgrp;
            const int r = base + rloc;
            float4 u = *reinterpret_cast<const float4*>(&Tf[rloc * 132 + c0]);
            float4 v = *reinterpret_cast<const float4*>(&Tf[rloc * 132 + c0 + 4]);
            float o[8] = {u.x, u.y, u.z, u.w, v.x, v.y, v.z, v.w};
            short8 ov;
#pragma unroll
            for (int j = 0; j < 8; ++j) {
                float t = o[j] + b2r[j];
                if (P1) t += b2f((unsigned short)p1v[p][j]);
                if (P2) t += b2f((unsigned short)p2v[p][j]);
                ov[j] = (short)f2b(fmaxf(t, 0.f));
            }
            if (r < M)
                *reinterpret_cast<short8*>(OB + (size_t)r * 128 + c0) = ov;
        }
    }
}

// ---------------------------------------------------------------------------
// F1: encoder + projection. h0 = A(f32,[M][K1])@W1T + b1 (no relu) -> OUT0;
// p1 = h0@W2T (no bias/relu) -> OUT1. K1 in {64,128}.
__global__ __launch_bounds__(256, 3) void fusedE(
    const float* __restrict__ A, int K1,
    const unsigned short* __restrict__ W1T, const float* __restrict__ b1,
    const unsigned short* __restrict__ W2T,
    unsigned short* __restrict__ OUT0, unsigned short* __restrict__ OUT1, int M)
{
    __shared__ float Tf[64 * 132];
    __shared__ unsigned short Tb[64 * 136];
    const int tid  = threadIdx.x;
    const int wave = tid >> 6;
    const int lane = tid & 63;
    const int quad = lane >> 4;
    const int l15  = lane & 15;
    const int base = blockIdx.x * 64;
    const int rgrp = tid >> 4;
    const int c0   = l15 * 8;
    const int nkk  = K1 >> 5;

    short8 af[4];
    {
        int r = base + wave * 16 + l15;
        int rc = (r < M) ? r : 0;
        const float* ap = A + (size_t)rc * K1 + quad * 8;
#pragma unroll
        for (int kk = 0; kk < 4; ++kk) if (kk < nkk) {
            float4 u = *reinterpret_cast<const float4*>(ap + kk * 32);
            float4 v = *reinterpret_cast<const float4*>(ap + kk * 32 + 4);
            short8 t;
            t[0] = (short)f2b(u.x); t[1] = (short)f2b(u.y);
            t[2] = (short)f2b(u.z); t[3] = (short)f2b(u.w);
            t[4] = (short)f2b(v.x); t[5] = (short)f2b(v.y);
            t[6] = (short)f2b(v.z); t[7] = (short)f2b(v.w);
            af[kk] = t;
        }
    }

    f32x4 acc[8];
#pragma unroll
    for (int nt = 0; nt < 8; ++nt) acc[nt] = (f32x4){0.f, 0.f, 0.f, 0.f};
#pragma unroll
    for (int nt = 0; nt < 8; ++nt) {
        const unsigned short* bp = W1T + (nt * 16 + l15) * K1 + quad * 8;
#pragma unroll
        for (int kk = 0; kk < 4; ++kk) if (kk < nkk) {
            short8 bf = *reinterpret_cast<const short8*>(bp + kk * 32);
            acc[nt] = __builtin_amdgcn_mfma_f32_16x16x32_bf16(
                af[kk], bf, acc[nt], 0, 0, 0);
        }
    }

    const int lrow0 = wave * 16 + quad * 4;
#pragma unroll
    for (int nt = 0; nt < 8; ++nt) {
        float bb = b1 ? b1[nt * 16 + l15] : 0.f;
#pragma unroll
        for (int reg = 0; reg < 4; ++reg)
            Tb[(lrow0 + reg) * 136 + nt * 16 + l15] = f2b(acc[nt][reg] + bb);
    }
    __syncthreads();

    // store h0 rows
#pragma unroll
    for (int p = 0; p < 4; ++p) {
        const int rloc = p * 16 + rgrp;
        const int r = base + rloc;
        if (r < M) {
            short8 hv = *reinterpret_cast<const short8*>(&Tb[rloc * 136 + c0]);
            *reinterpret_cast<short8*>(OUT0 + (size_t)r * 128 + c0) = hv;
        }
    }

    // stage 2: p1 = h0 @ W2T
    short8 af2[4];
#pragma unroll
    for (int kk = 0; kk < 4; ++kk)
        af2[kk] = *reinterpret_cast<const short8*>(
            &Tb[(wave * 16 + l15) * 136 + quad * 8 + kk * 32]);

    f32x4 acc2[8];
#pragma unroll
    for (int nt = 0; nt < 8; ++nt) acc2[nt] = (f32x4){0.f, 0.f, 0.f, 0.f};
#pragma unroll
    for (int nt = 0; nt < 8; ++nt) {
        const unsigned short* bp = W2T + (nt * 16 + l15) * 128 + quad * 8;
#pragma unroll
        for (int kk = 0; kk < 4; ++kk) {
            short8 bf = *reinterpret_cast<const short8*>(bp + kk * 32);
            acc2[nt] = __builtin_amdgcn_mfma_f32_16x16x32_bf16(
                af2[kk], bf, acc2[nt], 0, 0, 0);
        }
    }
#pragma unroll
    for (int nt = 0; nt < 8; ++nt)
#pragma unroll
        for (int reg = 0; reg < 4; ++reg)
            Tf[(lrow0 + reg) * 132 + nt * 16 + l15] = acc2[nt][reg];
    __syncthreads();
#pragma unroll
    for (int p = 0; p < 4; ++p) {
        const int rloc = p * 16 + rgrp;
        const int r = base + rloc;
        if (r >= M) continue;
        float4 u = *reinterpret_cast<const float4*>(&Tf[rloc * 132 + c0]);
        float4 v = *reinterpret_cast<const float4*>(&Tf[rloc * 132 + c0 + 4]);
        float o[8] = {u.x, u.y, u.z, u.w, v.x, v.y, v.z, v.w};
        short8 ov;
#pragma unroll
        for (int j = 0; j < 8; ++j) ov[j] = (short)f2b(o[j]);
        *reinterpret_cast<short8*>(OUT1 + (size_t)r * 128 + c0) = ov;
    }
}

// ---------------------------------------------------------------------------
// F2: update + projection. h1 = relu(A1@W1aT + A2@W1bT + b1) (LDS only);
// p2 = h1@W2T -> OUT1. A1,A2 bf16 [M][128]. h1 never hits HBM.
__global__ __launch_bounds__(256, 3) void fusedU(
    const unsigned short* __restrict__ A1, const unsigned short* __restrict__ A2,
    const unsigned short* __restrict__ W1aT, const unsigned short* __restrict__ W1bT,
    const float* __restrict__ b1,
    const unsigned short* __restrict__ W2T,
    unsigned short* __restrict__ OUT1, int M)
{
    __shared__ float Tf[64 * 132];
    __shared__ unsigned short Tb[64 * 136];
    const int tid  = threadIdx.x;
    const int wave = tid >> 6;
    const int lane = tid & 63;
    const int quad = lane >> 4;
    const int l15  = lane & 15;
    const int base = blockIdx.x * 64;
    const int rgrp = tid >> 4;
    const int c0   = l15 * 8;

    short8 afa[4], afb[4];
    {
        int r = base + wave * 16 + l15;
        int rc = (r < M) ? r : 0;
        const unsigned short* a1 = A1 + (size_t)rc * 128 + quad * 8;
        const unsigned short* a2 = A2 + (size_t)rc * 128 + quad * 8;
#pragma unroll
        for (int kk = 0; kk < 4; ++kk) {
            afa[kk] = *reinterpret_cast<const short8*>(a1 + kk * 32);
            afb[kk] = *reinterpret_cast<const short8*>(a2 + kk * 32);
        }
    }

    f32x4 acc[8];
#pragma unroll
    for (int nt = 0; nt < 8; ++nt) acc[nt] = (f32x4){0.f, 0.f, 0.f, 0.f};
#pragma unroll
    for (int nt = 0; nt < 8; ++nt) {
        const unsigned short* bpa = W1aT + (nt * 16 + l15) * 128 + quad * 8;
        const unsigned short* bpb = W1bT + (nt * 16 + l15) * 128 + quad * 8;
#pragma unroll
        for (int kk = 0; kk < 4; ++kk) {
            short8 ba = *reinterpret_cast<const short8*>(bpa + kk * 32);
            acc[nt] = __builtin_amdgcn_mfma_f32_16x16x32_bf16(
                afa[kk], ba, acc[nt], 0, 0, 0);
            short8 bb = *reinterpret_cast<const short8*>(bpb + kk * 32);
            acc[nt] = __builtin_amdgcn_mfma_f32_16x16x32_bf16(
                afb[kk], bb, acc[nt], 0, 0, 0);
        }
    }

    const int lrow0 = wave * 16 + quad * 4;
#pragma unroll
    for (int nt = 0; nt < 8; ++nt) {
        float bv = b1 ? b1[nt * 16 + l15] : 0.f;
#pragma unroll
        for (int reg = 0; reg < 4; ++reg)
            Tb[(lrow0 + reg) * 136 + nt * 16 + l15] =
                f2b(fmaxf(acc[nt][reg] + bv, 0.f));
    }
    __syncthreads();

    short8 af2[4];
#pragma unroll
    for (int kk = 0; kk < 4; ++kk)
        af2[kk] = *reinterpret_cast<const short8*>(
            &Tb[(wave * 16 + l15) * 136 + quad * 8 + kk * 32]);

    f32x4 acc2[8];
#pragma unroll
    for (int nt = 0; nt < 8; ++nt) acc2[nt] = (f32x4){0.f, 0.f, 0.f, 0.f};
#pragma unroll
    for (int nt = 0; nt < 8; ++nt) {
        const unsigned short* bp = W2T + (nt * 16 + l15) * 128 + quad * 8;
#pragma unroll
        for (int kk = 0; kk < 4; ++kk) {
            short8 bf = *reinterpret_cast<const short8*>(bp + kk * 32);
            acc2[nt] = __builtin_amdgcn_mfma_f32_16x16x32_bf16(
                af2[kk], bf, acc2[nt], 0, 0, 0);
        }
    }
#pragma unroll
    for (int nt = 0; nt < 8; ++nt)
#pragma unroll
        for (int reg = 0; reg < 4; ++reg)
            Tf[(lrow0 + reg) * 132 + nt * 16 + l15] = acc2[nt][reg];
    __syncthreads();
#pragma unroll
    for (int p = 0; p < 4; ++p) {
        const int rloc = p * 16 + rgrp;
        const int r = base + rloc;
        if (r >= M) continue;
        float4 u = *reinterpret_cast<const float4*>(&Tf[rloc * 132 + c0]);
        float4 v = *reinterpret_cast<const float4*>(&Tf[rloc * 132 + c0 + 4]);
        float o[8] = {u.x, u.y, u.z, u.w, v.x, v.y, v.z, v.w};
        short8 ov;
#pragma unroll
        for (int j = 0; j < 8; ++j) ov[j] = (short)f2b(o[j]);
        *reinterpret_cast<short8*>(OUT1 + (size_t)r * 128 + c0) = ov;
    }
}

// ---------------------------------------------------------------------------
// Weight prep: fp32 [K][128] -> bf16 transposed [128][K]; job 6/13 also does
// Wsum=Wr0+Wr2 and bsum=bl0+bl2. 18 jobs x 16384-short slots.
__global__ __launch_bounds__(256) void convert_weights(
    const float* __restrict__ tx_W, const float* __restrict__ card_proj_W,
    const float* __restrict__ merch_proj_W, const float* __restrict__ h1_W,
    const float* __restrict__ conv_Wl, const float* __restrict__ conv_Wr,
    const float* __restrict__ conv_bl,
    unsigned short* __restrict__ WT, float* __restrict__ bsum)
{
    int job = blockIdx.y;
    int K = 128;
    const float* src = nullptr;
    const float* src2 = nullptr;
    if (job == 0) src = tx_W;
    else if (job == 1) { src = card_proj_W; K = 64; }
    else if (job == 2) { src = merch_proj_W; K = 64; }
    else if (job == 3) src = h1_W;
    else {
        int l = (job - 4) / 7, e = (job - 4) % 7;
        const float* Wl = conv_Wl + (size_t)l * 4 * 16384;
        const float* Wr = conv_Wr + (size_t)l * 4 * 16384;
        switch (e) {
            case 0: src = Wl; break;
            case 1: src = Wl + 16384; break;
            case 2: src = Wl + 2 * 16384; break;
            case 3: src = Wl + 3 * 16384; break;
            case 4: src = Wr + 16384; break;
            case 5: src = Wr + 3 * 16384; break;
            default:
                src = Wr; src2 = Wr + 2 * 16384;
                if (blockIdx.x == 0 && threadIdx.x < 128) {
                    const float* bl = conv_bl + (size_t)l * 4 * 128;
                    bsum[l * 128 + threadIdx.x] =
                        bl[threadIdx.x] + bl[2 * 128 + threadIdx.x];
                }
                break;
        }
    }
    int e = blockIdx.x * 256 + threadIdx.x;
    if (e < (K << 7)) {
        int n = (K == 128) ? (e >> 7) : (e >> 6);
        int k = e & (K - 1);
        float v = src[(size_t)k * 128 + n];
        if (src2) v += src2[(size_t)k * 128 + n];
        WT[(size_t)job * 16384 + n * K + k] = f2b(v);
    }
}

// ---------------------------------------------------------------------------
// CSR build (edges fixed within call; reused across layers)
__global__ __launch_bounds__(256) void hist_kernel(
    const int* __restrict__ e_card, const int* __restrict__ e_merch,
    int* __restrict__ hist_c, int* __restrict__ hist_m, int E)
{
    int i = blockIdx.x * 256 + threadIdx.x;
    if (i < E) {
        atomicAdd(&hist_c[e_card[i]], 1);
        atomicAdd(&hist_m[e_merch[i]], 1);
    }
}

__global__ __launch_bounds__(1024) void scan2_kernel(
    const int* __restrict__ hist_c, int* __restrict__ offs_c, int* __restrict__ cur_c, int nc,
    const int* __restrict__ hist_m, int* __restrict__ offs_m, int* __restrict__ cur_m, int nm)
{
    const int* hist = (blockIdx.x == 0) ? hist_c : hist_m;
    int* offs = (blockIdx.x == 0) ? offs_c : offs_m;
    int* cursor = (blockIdx.x == 0) ? cur_c : cur_m;
    int n = (blockIdx.x == 0) ? nc : nm;
    __shared__ int wsum[16];
    __shared__ int s_carry;
    const int tid = threadIdx.x, lane = tid & 63, wid = tid >> 6;
    if (tid == 0) s_carry = 0;
    __syncthreads();
    for (int base = 0; base < n; base += 1024) {
        int i = base + tid;
        int v = (i < n) ? hist[i] : 0;
        int x = v;
#pragma unroll
        for (int d = 1; d < 64; d <<= 1) {
            int t = __shfl_up(x, d);
            if (lane >= d) x += t;
        }
        if (lane == 63) wsum[wid] = x;
        __syncthreads();
        if (wid == 0) {
            int y = (lane < 16) ? wsum[lane] : 0;
#pragma unroll
            for (int d = 1; d < 16; d <<= 1) {
                int t = __shfl_up(y, d);
                if (lane >= d) y += t;
            }
            if (lane < 16) wsum[lane] = y;
        }
        __syncthreads();
        int wbase = (wid > 0) ? wsum[wid - 1] : 0;
        int excl = s_carry + wbase + x - v;
        if (i < n) { offs[i] = excl; cursor[i] = excl; }
        __syncthreads();
        if (tid == 0) s_carry += wsum[15];
        __syncthreads();
    }
    if (threadIdx.x == 0) offs[n] = s_carry;
}

__global__ __launch_bounds__(256) void place_kernel(
    const int* __restrict__ e_card, const int* __restrict__ e_tx_c,
    const int* __restrict__ e_merch, const int* __restrict__ e_tx_m,
    int* __restrict__ cur_c, int* __restrict__ eidx_c,
    int* __restrict__ cur_m, int* __restrict__ eidx_m, int E)
{
    int i = blockIdx.x * 256 + threadIdx.x;
    if (i < E) {
        int pc = atomicAdd(&cur_c[e_card[i]], 1);
        eidx_c[pc] = e_tx_c[i];
        int pm = atomicAdd(&cur_m[e_merch[i]], 1);
        eidx_m[pm] = e_tx_m[i];
    }
}

// one wave per dst node; quad-per-edge, 16 lanes x 16B/row, shuffle reduce
__global__ __launch_bounds__(256) void gather_mean(
    const unsigned short* __restrict__ h_src, const int* __restrict__ offs,
    const int* __restrict__ eidx, unsigned short* __restrict__ out_mean, int n_dst)
{
    const int lane = threadIdx.x & 63;
    const int l15 = lane & 15;
    const int quad = lane >> 4;
    const int d = blockIdx.x * 4 + (threadIdx.x >> 6);
    if (d >= n_dst) return;
    const int s = offs[d], e = offs[d + 1];
    float a[8] = {0.f, 0.f, 0.f, 0.f, 0.f, 0.f, 0.f, 0.f};
    for (int p = s + quad; p < e; p += 4) {
        int tx = eidx[p];
        short8 v = *reinterpret_cast<const short8*>(
            h_src + (size_t)tx * 128 + l15 * 8);
#pragma unroll
        for (int j = 0; j < 8; ++j) a[j] += b2f((unsigned short)v[j]);
    }
#pragma unroll
    for (int j = 0; j < 8; ++j) {
        a[j] += __shfl_xor(a[j], 16);
        a[j] += __shfl_xor(a[j], 32);
    }
    if (quad == 0) {
        const float inv = (e > s) ? 1.0f / (float)(e - s) : 0.f;
        short8 o;
#pragma unroll
        for (int j = 0; j < 8; ++j) o[j] = (short)f2b(a[j] * inv);
        *reinterpret_cast<short8*>(out_mean + (size_t)d * 128 + l15 * 8) = o;
    }
}

// ---------------------------------------------------------------------------
extern "C" void kernel_launch(void* const* d_in, const int* in_sizes, int n_in,
                              void* d_out, int out_size, void* d_ws, size_t ws_size,
                              hipStream_t stream)
{
    const float* tx_x        = (const float*)d_in[0];
    const int*   e_card      = (const int*)d_in[3];
    const int*   e_tx_c      = (const int*)d_in[4];
    const int*   e_merch     = (const int*)d_in[5];
    const int*   e_tx_m      = (const int*)d_in[6];
    const float* card_emb    = (const float*)d_in[7];
    const float* merch_emb   = (const float*)d_in[8];
    const float* card_proj_W = (const float*)d_in[9];
    const float* card_proj_b = (const float*)d_in[10];
    const float* merch_proj_W= (const float*)d_in[11];
    const float* merch_proj_b= (const float*)d_in[12];
    const float* tx_W        = (const float*)d_in[13];
    const float* tx_b        = (const float*)d_in[14];
    const float* conv_Wl     = (const float*)d_in[15];
    const float* conv_bl     = (const float*)d_in[16];
    const float* conv_Wr     = (const float*)d_in[17];
    const float* h1_W        = (const float*)d_in[18];
    const float* h1_b        = (const float*)d_in[19];
    const float* h2_W        = (const float*)d_in[20];
    const float* h2_b        = (const float*)d_in[21];

    char* wsb = (char*)d_ws;
    auto alloc = [&](size_t bytes) {
        char* p = wsb; wsb += (bytes + 255) & ~(size_t)255; return p;
    };
    unsigned short* h_tx0      = (unsigned short*)alloc((size_t)N_TX * 128 * 2);
    unsigned short* h_tx1      = (unsigned short*)alloc((size_t)N_TX * 128 * 2);
    unsigned short* h_card0    = (unsigned short*)alloc((size_t)N_CARD * 128 * 2);
    unsigned short* h_merch0   = (unsigned short*)alloc((size_t)N_MERCH * 128 * 2);
    unsigned short* p_card     = (unsigned short*)alloc((size_t)N_CARD * 128 * 2);
    unsigned short* p_merch    = (unsigned short*)alloc((size_t)N_MERCH * 128 * 2);
    unsigned short* mean_card  = (unsigned short*)alloc((size_t)N_CARD * 128 * 2);
    unsigned short* mean_merch = (unsigned short*)alloc((size_t)N_MERCH * 128 * 2);
    unsigned short* WT         = (unsigned short*)alloc((size_t)18 * 16384 * 2);
    float* bsum = (float*)alloc(2 * 128 * 4);
    int* hist_c = (int*)alloc((size_t)(N_CARD + N_MERCH) * 4);  // one memset
    int* hist_m = hist_c + N_CARD;
    int* offs_c = (int*)alloc((size_t)(N_CARD + 1) * 4);
    int* cur_c  = (int*)alloc((size_t)N_CARD * 4);
    int* eidx_c = (int*)alloc((size_t)NE * 4);
    int* offs_m = (int*)alloc((size_t)(N_MERCH + 1) * 4);
    int* cur_m  = (int*)alloc((size_t)N_MERCH * 4);
    int* eidx_m = (int*)alloc((size_t)NE * 4);

    auto WTj = [&](int job) { return WT + (size_t)job * 16384; };

    // weight prep + CSR build
    convert_weights<<<dim3(64, 18), dim3(256), 0, stream>>>(
        tx_W, card_proj_W, merch_proj_W, h1_W, conv_Wl, conv_Wr, conv_bl,
        WT, bsum);
    hipMemsetAsync(hist_c, 0, (size_t)(N_CARD + N_MERCH) * 4, stream);
    hist_kernel<<<dim3((NE + 255) / 256), dim3(256), 0, stream>>>(
        e_card, e_merch, hist_c, hist_m, NE);
    scan2_kernel<<<dim3(2), dim3(1024), 0, stream>>>(
        hist_c, offs_c, cur_c, N_CARD, hist_m, offs_m, cur_m, N_MERCH);
    place_kernel<<<dim3((NE + 255) / 256), dim3(256), 0, stream>>>(
        e_card, e_tx_c, e_merch, e_tx_m, cur_c, eidx_c, cur_m, eidx_m, NE);

    // F1: encoder + layer-1 p-projection (card_ids/merch_ids are arange ->
    // identity gather). h0 -> HBM (needed for F2's Wr input); p1 -> HBM.
    fusedE<<<dim3((N_CARD + 63) / 64), dim3(256), 0, stream>>>(
        card_emb, 64, WTj(1), card_proj_b, WTj(4), h_card0, p_card, N_CARD);
    fusedE<<<dim3((N_MERCH + 63) / 64), dim3(256), 0, stream>>>(
        merch_emb, 64, WTj(2), merch_proj_b, WTj(6), h_merch0, p_merch, N_MERCH);

    // FUSED-A: tx encoder + layer-1 tx update
    fused2<<<dim3((N_TX + 63) / 64), dim3(256), 0, stream>>>(
        tx_x, 1, WTj(0), tx_b, WTj(10), bsum,
        p_card, e_card, p_merch, e_merch,
        h_tx0, nullptr, nullptr, h_tx1, N_TX);

    // layer-1 aggregation (reads h_tx0)
    gather_mean<<<dim3((N_CARD + 3) / 4), dim3(256), 0, stream>>>(
        h_tx0, offs_c, eidx_c, mean_card, N_CARD);
    gather_mean<<<dim3((N_MERCH + 3) / 4), dim3(256), 0, stream>>>(
        h_tx0, offs_m, eidx_m, mean_merch, N_MERCH);

    // F2: layer-1 card/merch update + layer-2 p-projection. h1 stays in LDS;
    // p2 overwrites the (now dead) p1 buffers.
    fusedU<<<dim3((N_CARD + 63) / 64), dim3(256), 0, stream>>>(
        mean_card, h_card0, WTj(5), WTj(8), conv_bl + 128, WTj(11),
        p_card, N_CARD);
    fusedU<<<dim3((N_MERCH + 63) / 64), dim3(256), 0, stream>>>(
        mean_merch, h_merch0, WTj(7), WTj(9), conv_bl + 3 * 128, WTj(13),
        p_merch, N_MERCH);

    // FUSED-B: layer-2 tx update + head (h_tx2 never hits HBM)
    fused2<<<dim3((N_TX + 63) / 64), dim3(256), 0, stream>>>(
        h_tx1, 0, WTj(17), bsum + 128, WTj(3), h1_b,
        p_card, e_card, p_merch, e_merch,
        nullptr, h2_W, h2_b, d_out, N_TX);
}